// Round 6
// baseline (513.727 us; speedup 1.0000x reference)
//
#include <hip/hip_runtime.h>

// VQ codebook nearest-neighbor: xs [32768,512] f32, W [8192,512] f32
// out[i] = W[argmin_j ||xs_i - W_j||^2]
//
// R6: pipelined f16 MFMA pass, 256x256 tile, 8 waves (2Mx4N), BK=32,
//     TRIPLE-buffered LDS (3x32KB) so STG(t+2) never touches a live buffer,
//     counted vmcnt(4) once per K-tile (never 0 in-loop), setprio MFMA
//     clusters, XOR-swizzled LDS (R2/R3-proven 0-conflict pattern).
//     + lean u32 best-2 epilogue + exact fp32 fixup for near-ties.

#define M_TOK 32768
#define N_EMB 8192
#define D_K   512
#define WOFF  2048.0f
#define QMASK 0xFFFFFF00u     // 8 low bits = local col (256-wide tile); quant step 0.0625
#define BAND  0.375f
#define NT    16              // K-tiles of 32

typedef _Float16 f16;
typedef __attribute__((ext_vector_type(8))) _Float16 f16x8;
typedef __attribute__((ext_vector_type(4))) _Float16 f16x4;
typedef __attribute__((ext_vector_type(4))) float f32x4;
typedef unsigned long long u64;
typedef unsigned int u32;

__device__ __forceinline__ void gload16(const void* g, void* l) {
  __builtin_amdgcn_global_load_lds(
      (const __attribute__((address_space(1))) unsigned int*)g,
      (__attribute__((address_space(3))) unsigned int*)l, 16, 0, 0);
}

__device__ __forceinline__ u32 map_f(float f) {   // exact order-preserving (fixup)
  u32 u = __float_as_uint(f);
  return u ^ ((u & 0x80000000u) ? 0xFFFFFFFFu : 0x80000000u);
}
__device__ __forceinline__ float qval(u32 key) {  // quantized approx value
  return __uint_as_float(key & QMASK) - WOFF;
}

// ---------------- wnorm (exact) + zero counter ----------------
__global__ __launch_bounds__(256) void wnorm_kernel(const float* __restrict__ w,
                                                    float* __restrict__ wnorm,
                                                    int* __restrict__ cnt) {
  if (blockIdx.x == 0 && threadIdx.x == 0) *cnt = 0;
  int row  = (blockIdx.x * 256 + threadIdx.x) >> 6;
  int lane = threadIdx.x & 63;
  if (row >= N_EMB) return;
  const float4* wr = (const float4*)(w + (size_t)row * D_K);
  float4 v0 = wr[lane * 2], v1 = wr[lane * 2 + 1];
  float s = v0.x*v0.x + v0.y*v0.y + v0.z*v0.z + v0.w*v0.w
          + v1.x*v1.x + v1.y*v1.y + v1.z*v1.z + v1.w*v1.w;
  #pragma unroll
  for (int off = 32; off; off >>= 1) s += __shfl_xor(s, off);
  if (lane == 0) wnorm[row] = s;
}

// ---------------- fp32 -> f16 (round-nearest) ----------------
__global__ __launch_bounds__(256) void convert_hi_kernel(const float* __restrict__ src,
                                                         f16* __restrict__ dst, int n4) {
  int e = blockIdx.x * 256 + threadIdx.x;
  if (e >= n4) return;
  float4 v = ((const float4*)src)[e];
  f16x4 h; h.x = (f16)v.x; h.y = (f16)v.y; h.z = (f16)v.z; h.w = (f16)v.w;
  *(f16x4*)(dst + (size_t)e * 4) = h;
}

// ---------------- pipelined approx distance + per-block best-2 ----------------
// LDS: 3 buffers x [A 16KB | B 16KB]. Iter t reads buf t%3, stages tile t+2
// into buf (t+2)%3 (== buf of tile t-1, whose reads finished >=2 barriers ago).
// vmcnt(4) per iter waits tile t+1 (issued one full iteration earlier).
__global__ __launch_bounds__(512, 2) void dist_mfma_kernel(
    const f16* __restrict__ Xh, const f16* __restrict__ Wh,
    const float* __restrict__ wnorm, uint2* __restrict__ partials) {
  __shared__ char smem[98304];

  int bid = (int)blockIdx.x;
  bid = (bid & 7) * 512 + (bid >> 3);           // XCD swizzle (4096 % 8 == 0)
  const int rt = bid >> 5, ct = bid & 31;
  const int row0 = rt * 256, col0 = ct * 256;

  const int tid  = threadIdx.x;
  const int w    = tid >> 6, lane = tid & 63;
  const int wr   = w >> 2,  wcn  = w & 3;       // 2 M-waves x 4 N-waves
  const int g    = lane >> 4, cl = lane & 15;

  const char* gA = (const char*)Xh + (size_t)row0 * 1024;   // row = 1024 B
  const char* gB = (const char*)Wh + (size_t)col0 * 1024;

  // per-thread stage source offsets (2 halves); dest is linear, src pre-swizzled
  int srcoff[2];
  #pragma unroll
  for (int h = 0; h < 2; ++h) {
    const int c  = h * 512 + tid;               // chunk 0..1023 (16B each)
    const int r  = c >> 2;                      // tile row 0..255
    const int kc = (c & 3) ^ ((r >> 1) & 3);    // pre-swizzled k-chunk
    srcoff[h] = r * 1024 + kc * 16;
  }
  const int ldsW = w * 1024;                    // wave-uniform dest base (+h*8192)

  #define STG_A(bo, kt)                                                        \
    { _Pragma("unroll") for (int h = 0; h < 2; ++h)                            \
        gload16(gA + srcoff[h] + (kt) * 64, smem + (bo) + h * 8192 + ldsW); }
  #define STG_B(bo, kt)                                                        \
    { _Pragma("unroll") for (int h = 0; h < 2; ++h)                            \
        gload16(gB + srcoff[h] + (kt) * 64, smem + (bo) + 16384 + h * 8192 + ldsW); }
  #define BARX()  asm volatile("s_barrier" ::: "memory")
  #define VMC(n)  asm volatile("s_waitcnt vmcnt(" #n ")" ::: "memory")

  f32x4 acc[8][4];
  #pragma unroll
  for (int i = 0; i < 8; i++)
    #pragma unroll
    for (int j = 0; j < 4; j++) acc[i][j] = (f32x4)(0.0f);

  // prologue: tile0 -> buf0, tile1 -> buf1; wait tile0 (tile1's 4 stay in flight)
  STG_A(0, 0);     STG_B(0, 0);
  STG_A(32768, 1); STG_B(32768, 1);
  VMC(4);
  BARX();

  int rb = 0;        // read-buffer byte offset (t%3)
  int sb = 65536;    // stage-buffer byte offset ((t+2)%3)
  f16x8 a[8], b[2];

  for (int t = 0; t < NT; ++t) {
    const int kt = (t + 2 < NT) ? (t + 2) : (NT - 1);   // phantom clamp (tail)
    // ---- phase A: read A + B(n01), stage A(t+2), MFMA n01 ----
    #pragma unroll
    for (int m = 0; m < 8; ++m) {
      const int rl = wr * 128 + m * 16 + cl;
      const int sl = g ^ ((rl >> 1) & 3);
      a[m] = *(const f16x8*)(smem + rb + rl * 64 + sl * 16);
    }
    #pragma unroll
    for (int n = 0; n < 2; ++n) {
      const int rl = wcn * 64 + n * 16 + cl;
      const int sl = g ^ ((rl >> 1) & 3);
      b[n] = *(const f16x8*)(smem + rb + 16384 + rl * 64 + sl * 16);
    }
    STG_A(sb, kt);
    BARX();
    __builtin_amdgcn_s_setprio(1);
    #pragma unroll
    for (int m = 0; m < 8; ++m) {
      acc[m][0] = __builtin_amdgcn_mfma_f32_16x16x32_f16(a[m], b[0], acc[m][0], 0, 0, 0);
      acc[m][1] = __builtin_amdgcn_mfma_f32_16x16x32_f16(a[m], b[1], acc[m][1], 0, 0, 0);
    }
    __builtin_amdgcn_s_setprio(0);
    BARX();
    // ---- phase B: read B(n23), stage B(t+2), wait tile t+1, MFMA n23 ----
    #pragma unroll
    for (int n = 0; n < 2; ++n) {
      const int rl = wcn * 64 + (2 + n) * 16 + cl;
      const int sl = g ^ ((rl >> 1) & 3);
      b[n] = *(const f16x8*)(smem + rb + 16384 + rl * 64 + sl * 16);
    }
    STG_B(sb, kt);
    VMC(4);          // tile t+1 landed; tile t+2's 4 loads remain in flight
    BARX();
    __builtin_amdgcn_s_setprio(1);
    #pragma unroll
    for (int m = 0; m < 8; ++m) {
      acc[m][2] = __builtin_amdgcn_mfma_f32_16x16x32_f16(a[m], b[0], acc[m][2], 0, 0, 0);
      acc[m][3] = __builtin_amdgcn_mfma_f32_16x16x32_f16(a[m], b[1], acc[m][3], 0, 0, 0);
    }
    __builtin_amdgcn_s_setprio(0);
    BARX();
    rb = (rb == 65536) ? 0 : rb + 32768;
    sb = (sb == 65536) ? 0 : sb + 32768;
  }
  #undef STG_A
  #undef STG_B

  VMC(0);            // drain phantom DMAs before LDS reuse
  __syncthreads();

  // ---- epilogue: u32 keys (quantized bits | 8-bit local col), best-2 ----
  float wnp[4];
  u32 colb[4];
  #pragma unroll
  for (int n = 0; n < 4; ++n) {
    wnp[n]  = wnorm[col0 + wcn * 64 + n * 16 + cl] + WOFF;
    colb[n] = (u32)(wcn * 64 + n * 16 + cl);
  }

  uint2* cmb = (uint2*)smem;   // [256 rows][4 wcn] = 8KB

  #pragma unroll
  for (int m = 0; m < 8; ++m) {
    #pragma unroll
    for (int r = 0; r < 4; ++r) {
      float s0 = fmaf(-2.0f, acc[m][0][r], wnp[0]);
      float s1 = fmaf(-2.0f, acc[m][1][r], wnp[1]);
      float s2 = fmaf(-2.0f, acc[m][2][r], wnp[2]);
      float s3 = fmaf(-2.0f, acc[m][3][r], wnp[3]);
      u32 k0 = (__float_as_uint(s0) & QMASK) | colb[0];
      u32 k1 = (__float_as_uint(s1) & QMASK) | colb[1];
      u32 k2 = (__float_as_uint(s2) & QMASK) | colb[2];
      u32 k3 = (__float_as_uint(s3) & QMASK) | colb[3];
      u32 pa = min(k0, k1), pb = max(k0, k1);
      u32 pc = min(k2, k3), pd = max(k2, k3);
      u32 c1 = min(pa, pc);
      u32 c2 = min(max(pa, pc), min(pb, pd));
      #pragma unroll
      for (int off = 1; off < 16; off <<= 1) {
        u32 o1 = __shfl_xor(c1, off), o2 = __shfl_xor(c2, off);
        u32 n1 = min(c1, o1);
        c2 = min(min(c2, o2), max(c1, o1));
        c1 = n1;
      }
      if (cl == 0) cmb[(wr * 128 + m * 16 + g * 4 + r) * 4 + wcn] = make_uint2(c1, c2);
    }
  }
  __syncthreads();
  if (tid < 256) {
    u32 b1 = 0xFFFFFFFFu, b2 = 0xFFFFFFFFu;
    #pragma unroll
    for (int q = 0; q < 4; ++q) {
      uint2 e = cmb[tid * 4 + q];
      u32 m1 = min(b1, e.x);
      b2 = min(max(b1, e.x), min(b2, e.y));
      b1 = m1;
    }
    partials[(size_t)ct * M_TOK + row0 + tid] = make_uint2(b1, b2);
  }
}

// ---------------- global best-2 + flag near-ties ----------------
__global__ __launch_bounds__(256) void reduce_kernel(
    const uint2* __restrict__ partials, u32* __restrict__ bestkey,
    int* __restrict__ fidx, int* __restrict__ flaglist, int* __restrict__ cnt) {
  int t = blockIdx.x * 256 + threadIdx.x;
  if (t >= M_TOK) return;
  u32 b1 = 0xFFFFFFFFu, b2 = 0xFFFFFFFFu;
  int bidx = 0;
  for (int ct = 0; ct < 32; ++ct) {
    uint2 e = partials[(size_t)ct * M_TOK + t];
    if (e.x < b1) {
      b2 = min(b1, min(b2, e.y));
      b1 = e.x;
      bidx = ct * 256 + (int)(e.x & 255u);
    } else {
      b2 = min(b2, e.x);
    }
  }
  bestkey[t] = b1;
  fidx[t] = bidx;
  if (qval(b2) - qval(b1) < BAND) flaglist[atomicAdd(cnt, 1)] = t;
}

// ---------------- exact fp32 re-rank for flagged tokens ----------------
__global__ __launch_bounds__(256) void fixup_kernel(
    const float* __restrict__ xs, const float* __restrict__ w,
    const float* __restrict__ wnorm, const uint2* __restrict__ partials,
    const u32* __restrict__ bestkey, const int* __restrict__ flaglist,
    const int* __restrict__ cnt, int* __restrict__ fidx) {
  __shared__ int s_cand[8256];
  __shared__ int s_n;
  __shared__ u64 s_best;
  const int n_flag = *cnt;
  for (int ii = blockIdx.x; ii < n_flag; ii += gridDim.x) {
    const int t = flaglist[ii];
    if (threadIdx.x == 0) { s_n = 0; s_best = ~0ULL; }
    __syncthreads();
    const float thr = qval(bestkey[t]) + BAND;
    if (threadIdx.x < 32) {
      uint2 e = partials[(size_t)threadIdx.x * M_TOK + t];
      if (qval(e.x) <= thr)
        s_cand[atomicAdd(&s_n, 1)] = (int)threadIdx.x * 256 + (int)(e.x & 255u);
      if (qval(e.y) <= thr) {                // possible hidden 3rd: scan whole block
        int base = atomicAdd(&s_n, 256);
        for (int c = 0; c < 256; ++c) s_cand[base + c] = (int)threadIdx.x * 256 + c;
      }
    }
    __syncthreads();
    const int n = s_n;
    const int wid = threadIdx.x >> 6, lane = threadIdx.x & 63;
    for (int c = wid; c < n; c += 4) {
      const int j = s_cand[c];
      const float4* xr = (const float4*)(xs + (size_t)t * D_K);
      const float4* wr = (const float4*)(w + (size_t)j * D_K);
      float4 a0 = xr[lane * 2], a1 = xr[lane * 2 + 1];
      float4 b0 = wr[lane * 2], b1 = wr[lane * 2 + 1];
      float s = a0.x*b0.x + a0.y*b0.y + a0.z*b0.z + a0.w*b0.w
              + a1.x*b1.x + a1.y*b1.y + a1.z*b1.z + a1.w*b1.w;
      #pragma unroll
      for (int off = 32; off; off >>= 1) s += __shfl_xor(s, off);
      if (lane == 0) {
        float score = wnorm[j] - 2.0f * s;
        u64 k = ((u64)map_f(score) << 32) | (u32)j;
        atomicMin(&s_best, k);
      }
    }
    __syncthreads();
    if (threadIdx.x == 0) fidx[t] = (int)(s_best & 0xFFFFFFFFULL);
    __syncthreads();
  }
}

// ---------------- gather: out = xs + (W[idx] - xs) ----------------
__global__ __launch_bounds__(256) void gather_kernel(const float* __restrict__ xs,
                                                     const float* __restrict__ w,
                                                     const int* __restrict__ fidx,
                                                     float* __restrict__ out) {
  int e = blockIdx.x * 256 + threadIdx.x;
  int row = e >> 7, off = e & 127;
  float4 xv = ((const float4*)(xs + (size_t)row * D_K))[off];
  float4 wv = ((const float4*)(w  + (size_t)fidx[row] * D_K))[off];
  float4 o;
  o.x = xv.x + (wv.x - xv.x);
  o.y = xv.y + (wv.y - xv.y);
  o.z = xv.z + (wv.z - xv.z);
  o.w = xv.w + (wv.w - xv.w);
  ((float4*)out)[e] = o;
}

extern "C" void kernel_launch(void* const* d_in, const int* in_sizes, int n_in,
                              void* d_out, int out_size, void* d_ws, size_t ws_size,
                              hipStream_t stream) {
  const float* xs = (const float*)d_in[0];
  const float* w  = (const float*)d_in[1];
  float* out = (float*)d_out;

  // ws layout (~51 MB; ws proven >= 85 MB in R2)
  char* p = (char*)d_ws;
  f16*   Xh       = (f16*)p;                 p += (size_t)M_TOK * D_K * 2;
  f16*   Wh       = (f16*)p;                 p += (size_t)N_EMB * D_K * 2;
  float* wnorm    = (float*)p;               p += (size_t)N_EMB * 4;
  uint2* partials = (uint2*)p;               p += (size_t)32 * M_TOK * 8;
  u32*   bestkey  = (u32*)p;                 p += (size_t)M_TOK * 4;
  int*   fidx     = (int*)p;                 p += (size_t)M_TOK * 4;
  int*   flaglist = (int*)p;                 p += (size_t)M_TOK * 4;
  int*   cnt      = (int*)p;

  convert_hi_kernel<<<(M_TOK * 128) / 256, 256, 0, stream>>>(xs, Xh, M_TOK * 128);
  convert_hi_kernel<<<(N_EMB * 128) / 256, 256, 0, stream>>>(w,  Wh, N_EMB * 128);
  wnorm_kernel<<<N_EMB / 4, 256, 0, stream>>>(w, wnorm, cnt);
  dist_mfma_kernel<<<(M_TOK / 256) * (N_EMB / 256), 512, 0, stream>>>(Xh, Wh, wnorm, partials);
  reduce_kernel<<<M_TOK / 256, 256, 0, stream>>>(partials, bestkey, fidx, flaglist, cnt);
  fixup_kernel<<<256, 256, 0, stream>>>(xs, w, wnorm, partials, bestkey, flaglist, cnt, fidx);
  gather_kernel<<<(M_TOK * (D_K / 4)) / 256, 256, 0, stream>>>(xs, w, fidx, out);
}

// Round 7
// 494.355 us; speedup vs baseline: 1.0392x; 1.0392x over previous
//
#include <hip/hip_runtime.h>

// VQ codebook nearest-neighbor: xs [32768,512] f32, W [8192,512] f32
// out[i] = W[argmin_j ||xs_i - W_j||^2]
//
// R7: f16 MFMA approx pass, 256x256 tile, 8 waves (2Mx4N), BK=32,
//     4-buffer LDS rotation (4x32KB=128KB), register-level A-prefetch:
//     tile t issues b(t) + a(t+1) reads, so the A LDS-drain hides under
//     tile t's MFMAs. One {vmcnt(4) lgkmcnt(0); s_barrier} per tile
//     (counted vmcnt, never 0 until tail). Fully unrolled K-loop ->
//     static register ping-pong. + lean u32 best-2 epilogue + exact
//     fp32 fixup for near-tie tokens (R6-proven).

#define M_TOK 32768
#define N_EMB 8192
#define D_K   512
#define WOFF  2048.0f
#define QMASK 0xFFFFFF00u     // 8 low bits = local col; quant step 0.0625
#define BAND  0.375f
#define NT    16              // K-tiles of 32

typedef _Float16 f16;
typedef __attribute__((ext_vector_type(8))) _Float16 f16x8;
typedef __attribute__((ext_vector_type(4))) _Float16 f16x4;
typedef __attribute__((ext_vector_type(4))) float f32x4;
typedef unsigned long long u64;
typedef unsigned int u32;

__device__ __forceinline__ void gload16(const void* g, void* l) {
  __builtin_amdgcn_global_load_lds(
      (const __attribute__((address_space(1))) unsigned int*)g,
      (__attribute__((address_space(3))) unsigned int*)l, 16, 0, 0);
}

__device__ __forceinline__ u32 map_f(float f) {   // exact order-preserving (fixup)
  u32 u = __float_as_uint(f);
  return u ^ ((u & 0x80000000u) ? 0xFFFFFFFFu : 0x80000000u);
}
__device__ __forceinline__ float qval(u32 key) {  // quantized approx value
  return __uint_as_float(key & QMASK) - WOFF;
}

// ---------------- wnorm (exact) + zero counter ----------------
__global__ __launch_bounds__(256) void wnorm_kernel(const float* __restrict__ w,
                                                    float* __restrict__ wnorm,
                                                    int* __restrict__ cnt) {
  if (blockIdx.x == 0 && threadIdx.x == 0) *cnt = 0;
  int row  = (blockIdx.x * 256 + threadIdx.x) >> 6;
  int lane = threadIdx.x & 63;
  if (row >= N_EMB) return;
  const float4* wr = (const float4*)(w + (size_t)row * D_K);
  float4 v0 = wr[lane * 2], v1 = wr[lane * 2 + 1];
  float s = v0.x*v0.x + v0.y*v0.y + v0.z*v0.z + v0.w*v0.w
          + v1.x*v1.x + v1.y*v1.y + v1.z*v1.z + v1.w*v1.w;
  #pragma unroll
  for (int off = 32; off; off >>= 1) s += __shfl_xor(s, off);
  if (lane == 0) wnorm[row] = s;
}

// ---------------- fp32 -> f16 (round-nearest) ----------------
__global__ __launch_bounds__(256) void convert_hi_kernel(const float* __restrict__ src,
                                                         f16* __restrict__ dst, int n4) {
  int e = blockIdx.x * 256 + threadIdx.x;
  if (e >= n4) return;
  float4 v = ((const float4*)src)[e];
  f16x4 h; h.x = (f16)v.x; h.y = (f16)v.y; h.z = (f16)v.z; h.w = (f16)v.w;
  *(f16x4*)(dst + (size_t)e * 4) = h;
}

// ---------------- pipelined approx distance + per-block best-2 ----------------
// 4 buffers x [A 16KB | B 16KB]. Tile tau lives in buf tau%4.
// Iter t: read b(t) from buf t%4, prefetch a(t+1) regs from buf (t+1)%4,
// stage tile t+3 into buf (t+3)%4, 32 MFMA (compiler lgkm-splits waits),
// then {vmcnt(4) lgkmcnt(0); s_barrier}.
// Hazard proof: buf (t+3)%4 holds tile t-1; its last reads (b(t-1)) were
// consumed by MFMAs in iter t-1 and lgkmcnt(0)-drained before BAR(t-1);
// S(t+3) is issued after BAR(t-1). a(t+1)-prefetch safety: buf (t+1)%4
// staged as S(t+1) at iter t-2; vmcnt(4) at iter t-1 leaves only S(t+2)
// outstanding -> S(t+1) landed. Tail: t>=13 uses vmcnt(0) (S(15) issued
// >=1 full iter earlier -> no stall).
__global__ __launch_bounds__(512, 2) void dist_mfma_kernel(
    const f16* __restrict__ Xh, const f16* __restrict__ Wh,
    const float* __restrict__ wnorm, uint2* __restrict__ partials) {
  __shared__ char smem[131072];

  int bid = (int)blockIdx.x;
  bid = (bid & 7) * 512 + (bid >> 3);           // XCD swizzle (4096 % 8 == 0)
  const int rt = bid >> 5, ct = bid & 31;
  const int row0 = rt * 256, col0 = ct * 256;

  const int tid  = threadIdx.x;
  const int w    = tid >> 6, lane = tid & 63;
  const int wr   = w >> 2,  wcn  = w & 3;       // 2 M-waves x 4 N-waves
  const int g    = lane >> 4, cl = lane & 15;

  const char* gA = (const char*)Xh + (size_t)row0 * 1024;   // row = 1024 B
  const char* gB = (const char*)Wh + (size_t)col0 * 1024;

  // stage source offsets (pre-swizzled); dest is linear chunk c = h*512+tid
  int srcoff[2];
  #pragma unroll
  for (int h = 0; h < 2; ++h) {
    const int c  = h * 512 + tid;
    const int r  = c >> 2;
    const int kc = (c & 3) ^ ((r >> 1) & 3);
    srcoff[h] = r * 1024 + kc * 16;
  }
  const int ldsW = w * 1024;

  // per-thread LDS read byte-offsets (within a buffer)
  int offA[8], offB[4];
  #pragma unroll
  for (int m = 0; m < 8; ++m) {
    const int rl = wr * 128 + m * 16 + cl;
    offA[m] = rl * 64 + (g ^ ((rl >> 1) & 3)) * 16;
  }
  #pragma unroll
  for (int n = 0; n < 4; ++n) {
    const int rl = wcn * 64 + n * 16 + cl;
    offB[n] = 16384 + rl * 64 + (g ^ ((rl >> 1) & 3)) * 16;
  }

  #define STG_A(bo, kt)                                                        \
    { _Pragma("unroll") for (int h = 0; h < 2; ++h)                            \
        gload16(gA + srcoff[h] + (kt) * 64, smem + (bo) + h * 8192 + ldsW); }
  #define STG_B(bo, kt)                                                        \
    { _Pragma("unroll") for (int h = 0; h < 2; ++h)                            \
        gload16(gB + srcoff[h] + (kt) * 64, smem + (bo) + 16384 + h * 8192 + ldsW); }

  f32x4 acc[8][4];
  #pragma unroll
  for (int i = 0; i < 8; i++)
    #pragma unroll
    for (int j = 0; j < 4; j++) acc[i][j] = (f32x4)(0.0f);

  // prologue: stage tiles 0,1,2; wait until S0,S1 landed (<=4 outstanding)
  STG_A(0, 0);     STG_B(0, 0);
  STG_A(32768, 1); STG_B(32768, 1);
  STG_A(65536, 2); STG_B(65536, 2);
  asm volatile("s_waitcnt vmcnt(4)\ns_barrier" ::: "memory");

  f16x8 aP[8], aQ[8];
  #pragma unroll
  for (int m = 0; m < 8; ++m) aP[m] = *(const f16x8*)(smem + offA[m]);

  #define TILE(t, AC, AN)                                                      \
    {                                                                          \
      constexpr int rb = ((t) % 4) * 32768;                                    \
      constexpr int nb = (((t) + 1) % 4) * 32768;                              \
      constexpr int sb = (((t) + 3) % 4) * 32768;                              \
      f16x8 b0 = *(const f16x8*)(smem + rb + offB[0]);                         \
      f16x8 b1 = *(const f16x8*)(smem + rb + offB[1]);                         \
      f16x8 b2 = *(const f16x8*)(smem + rb + offB[2]);                         \
      f16x8 b3 = *(const f16x8*)(smem + rb + offB[3]);                         \
      if ((t) < NT - 1) {                                                      \
        _Pragma("unroll") for (int m = 0; m < 8; ++m)                          \
          AN[m] = *(const f16x8*)(smem + nb + offA[m]);                        \
      }                                                                        \
      if ((t) + 3 < NT) { STG_A(sb, (t) + 3); STG_B(sb, (t) + 3); }            \
      __builtin_amdgcn_s_setprio(1);                                           \
      _Pragma("unroll") for (int m = 0; m < 8; ++m) {                          \
        acc[m][0] = __builtin_amdgcn_mfma_f32_16x16x32_f16(AC[m], b0, acc[m][0], 0, 0, 0); \
        acc[m][1] = __builtin_amdgcn_mfma_f32_16x16x32_f16(AC[m], b1, acc[m][1], 0, 0, 0); \
      }                                                                        \
      _Pragma("unroll") for (int m = 0; m < 8; ++m) {                          \
        acc[m][2] = __builtin_amdgcn_mfma_f32_16x16x32_f16(AC[m], b2, acc[m][2], 0, 0, 0); \
        acc[m][3] = __builtin_amdgcn_mfma_f32_16x16x32_f16(AC[m], b3, acc[m][3], 0, 0, 0); \
      }                                                                        \
      __builtin_amdgcn_s_setprio(0);                                           \
      if ((t) < 13) { asm volatile("s_waitcnt vmcnt(4) lgkmcnt(0)\ns_barrier" ::: "memory"); } \
      else          { asm volatile("s_waitcnt vmcnt(0) lgkmcnt(0)\ns_barrier" ::: "memory"); } \
    }

  TILE(0,  aP, aQ)  TILE(1,  aQ, aP)  TILE(2,  aP, aQ)  TILE(3,  aQ, aP)
  TILE(4,  aP, aQ)  TILE(5,  aQ, aP)  TILE(6,  aP, aQ)  TILE(7,  aQ, aP)
  TILE(8,  aP, aQ)  TILE(9,  aQ, aP)  TILE(10, aP, aQ)  TILE(11, aQ, aP)
  TILE(12, aP, aQ)  TILE(13, aQ, aP)  TILE(14, aP, aQ)  TILE(15, aQ, aP)

  #undef TILE
  #undef STG_A
  #undef STG_B

  // ---- epilogue: u32 keys (quantized bits | 8-bit local col), best-2 ----
  float wnp[4];
  u32 colb[4];
  #pragma unroll
  for (int n = 0; n < 4; ++n) {
    wnp[n]  = wnorm[col0 + wcn * 64 + n * 16 + cl] + WOFF;
    colb[n] = (u32)(wcn * 64 + n * 16 + cl);
  }

  uint2* cmb = (uint2*)smem;   // [256 rows][4 wcn] = 8KB (loop fully drained)

  #pragma unroll
  for (int m = 0; m < 8; ++m) {
    #pragma unroll
    for (int r = 0; r < 4; ++r) {
      float s0 = fmaf(-2.0f, acc[m][0][r], wnp[0]);
      float s1 = fmaf(-2.0f, acc[m][1][r], wnp[1]);
      float s2 = fmaf(-2.0f, acc[m][2][r], wnp[2]);
      float s3 = fmaf(-2.0f, acc[m][3][r], wnp[3]);
      u32 k0 = (__float_as_uint(s0) & QMASK) | colb[0];
      u32 k1 = (__float_as_uint(s1) & QMASK) | colb[1];
      u32 k2 = (__float_as_uint(s2) & QMASK) | colb[2];
      u32 k3 = (__float_as_uint(s3) & QMASK) | colb[3];
      u32 pa = min(k0, k1), pb = max(k0, k1);
      u32 pc = min(k2, k3), pd = max(k2, k3);
      u32 c1 = min(pa, pc);
      u32 c2 = min(max(pa, pc), min(pb, pd));
      #pragma unroll
      for (int off = 1; off < 16; off <<= 1) {
        u32 o1 = __shfl_xor(c1, off), o2 = __shfl_xor(c2, off);
        u32 n1 = min(c1, o1);
        c2 = min(min(c2, o2), max(c1, o1));
        c1 = n1;
      }
      if (cl == 0) cmb[(wr * 128 + m * 16 + g * 4 + r) * 4 + wcn] = make_uint2(c1, c2);
    }
  }
  __syncthreads();
  if (tid < 256) {
    u32 b1 = 0xFFFFFFFFu, b2 = 0xFFFFFFFFu;
    #pragma unroll
    for (int q = 0; q < 4; ++q) {
      uint2 e = cmb[tid * 4 + q];
      u32 m1 = min(b1, e.x);
      b2 = min(max(b1, e.x), min(b2, e.y));
      b1 = m1;
    }
    partials[(size_t)ct * M_TOK + row0 + tid] = make_uint2(b1, b2);
  }
}

// ---------------- global best-2 + flag near-ties ----------------
__global__ __launch_bounds__(256) void reduce_kernel(
    const uint2* __restrict__ partials, u32* __restrict__ bestkey,
    int* __restrict__ fidx, int* __restrict__ flaglist, int* __restrict__ cnt) {
  int t = blockIdx.x * 256 + threadIdx.x;
  if (t >= M_TOK) return;
  u32 b1 = 0xFFFFFFFFu, b2 = 0xFFFFFFFFu;
  int bidx = 0;
  for (int ct = 0; ct < 32; ++ct) {
    uint2 e = partials[(size_t)ct * M_TOK + t];
    if (e.x < b1) {
      b2 = min(b1, min(b2, e.y));
      b1 = e.x;
      bidx = ct * 256 + (int)(e.x & 255u);
    } else {
      b2 = min(b2, e.x);
    }
  }
  bestkey[t] = b1;
  fidx[t] = bidx;
  if (qval(b2) - qval(b1) < BAND) flaglist[atomicAdd(cnt, 1)] = t;
}

// ---------------- exact fp32 re-rank for flagged tokens ----------------
__global__ __launch_bounds__(256) void fixup_kernel(
    const float* __restrict__ xs, const float* __restrict__ w,
    const float* __restrict__ wnorm, const uint2* __restrict__ partials,
    const u32* __restrict__ bestkey, const int* __restrict__ flaglist,
    const int* __restrict__ cnt, int* __restrict__ fidx) {
  __shared__ int s_cand[8256];
  __shared__ int s_n;
  __shared__ u64 s_best;
  const int n_flag = *cnt;
  for (int ii = blockIdx.x; ii < n_flag; ii += gridDim.x) {
    const int t = flaglist[ii];
    if (threadIdx.x == 0) { s_n = 0; s_best = ~0ULL; }
    __syncthreads();
    const float thr = qval(bestkey[t]) + BAND;
    if (threadIdx.x < 32) {
      uint2 e = partials[(size_t)threadIdx.x * M_TOK + t];
      if (qval(e.x) <= thr)
        s_cand[atomicAdd(&s_n, 1)] = (int)threadIdx.x * 256 + (int)(e.x & 255u);
      if (qval(e.y) <= thr) {                // possible hidden 3rd: scan whole block
        int base = atomicAdd(&s_n, 256);
        for (int c = 0; c < 256; ++c) s_cand[base + c] = (int)threadIdx.x * 256 + c;
      }
    }
    __syncthreads();
    const int n = s_n;
    const int wid = threadIdx.x >> 6, lane = threadIdx.x & 63;
    for (int c = wid; c < n; c += 4) {
      const int j = s_cand[c];
      const float4* xr = (const float4*)(xs + (size_t)t * D_K);
      const float4* wr = (const float4*)(w + (size_t)j * D_K);
      float4 a0 = xr[lane * 2], a1 = xr[lane * 2 + 1];
      float4 b0 = wr[lane * 2], b1 = wr[lane * 2 + 1];
      float s = a0.x*b0.x + a0.y*b0.y + a0.z*b0.z + a0.w*b0.w
              + a1.x*b1.x + a1.y*b1.y + a1.z*b1.z + a1.w*b1.w;
      #pragma unroll
      for (int off = 32; off; off >>= 1) s += __shfl_xor(s, off);
      if (lane == 0) {
        float score = wnorm[j] - 2.0f * s;
        u64 k = ((u64)map_f(score) << 32) | (u32)j;
        atomicMin(&s_best, k);
      }
    }
    __syncthreads();
    if (threadIdx.x == 0) fidx[t] = (int)(s_best & 0xFFFFFFFFULL);
    __syncthreads();
  }
}

// ---------------- gather: out = xs + (W[idx] - xs) ----------------
__global__ __launch_bounds__(256) void gather_kernel(const float* __restrict__ xs,
                                                     const float* __restrict__ w,
                                                     const int* __restrict__ fidx,
                                                     float* __restrict__ out) {
  int e = blockIdx.x * 256 + threadIdx.x;
  int row = e >> 7, off = e & 127;
  float4 xv = ((const float4*)(xs + (size_t)row * D_K))[off];
  float4 wv = ((const float4*)(w  + (size_t)fidx[row] * D_K))[off];
  float4 o;
  o.x = xv.x + (wv.x - xv.x);
  o.y = xv.y + (wv.y - xv.y);
  o.z = xv.z + (wv.z - xv.z);
  o.w = xv.w + (wv.w - xv.w);
  ((float4*)out)[e] = o;
}

extern "C" void kernel_launch(void* const* d_in, const int* in_sizes, int n_in,
                              void* d_out, int out_size, void* d_ws, size_t ws_size,
                              hipStream_t stream) {
  const float* xs = (const float*)d_in[0];
  const float* w  = (const float*)d_in[1];
  float* out = (float*)d_out;

  // ws layout (~51 MB; ws proven >= 85 MB in R2)
  char* p = (char*)d_ws;
  f16*   Xh       = (f16*)p;                 p += (size_t)M_TOK * D_K * 2;
  f16*   Wh       = (f16*)p;                 p += (size_t)N_EMB * D_K * 2;
  float* wnorm    = (float*)p;               p += (size_t)N_EMB * 4;
  uint2* partials = (uint2*)p;               p += (size_t)32 * M_TOK * 8;
  u32*   bestkey  = (u32*)p;                 p += (size_t)M_TOK * 4;
  int*   fidx     = (int*)p;                 p += (size_t)M_TOK * 4;
  int*   flaglist = (int*)p;                 p += (size_t)M_TOK * 4;
  int*   cnt      = (int*)p;

  convert_hi_kernel<<<(M_TOK * 128) / 256, 256, 0, stream>>>(xs, Xh, M_TOK * 128);
  convert_hi_kernel<<<(N_EMB * 128) / 256, 256, 0, stream>>>(w,  Wh, N_EMB * 128);
  wnorm_kernel<<<N_EMB / 4, 256, 0, stream>>>(w, wnorm, cnt);
  dist_mfma_kernel<<<(M_TOK / 256) * (N_EMB / 256), 512, 0, stream>>>(Xh, Wh, wnorm, partials);
  reduce_kernel<<<M_TOK / 256, 256, 0, stream>>>(partials, bestkey, fidx, flaglist, cnt);
  fixup_kernel<<<256, 256, 0, stream>>>(xs, w, wnorm, partials, bestkey, flaglist, cnt, fidx);
  gather_kernel<<<(M_TOK * (D_K / 4)) / 256, 256, 0, stream>>>(xs, w, fidx, out);
}